// Round 7
// baseline (23.115 us; speedup 1.0000x reference)
//
#include <hip/hip_runtime.h>

#define TILE 256           // square tile side; block = 256 threads, j per-lane
#define MAGIC 0x5AFEC0DEu  // per-slot flag value: MAGIC ^ slot

__global__ __launch_bounds__(256) void cindex_onepass_kernel(
    const float* __restrict__ risk,
    const float* __restrict__ tim,
    const int*   __restrict__ evt,
    unsigned int* __restrict__ part,    // SoA: [0,nblk)=conc, [nblk,2n)=tie, [2n,3n)=comp
    unsigned int* __restrict__ flags,   // [3*nblk, 4*nblk): per-block done sentinel
    float* __restrict__ out,
    int n, int nblk)
{
    const int t = blockIdx.x;
    // Decode lower-triangle pair (p >= q): p*(p+1)/2 <= t < (p+1)*(p+2)/2
    int p = (int)((sqrtf(8.0f * (float)t + 1.0f) - 1.0f) * 0.5f);
    while ((p + 1) * (p + 2) / 2 <= t) ++p;
    while (p * (p + 1) / 2 > t) --p;
    const int q = t - p * (p + 1) / 2;

    const int i0 = q * TILE;          // i-tile (smaller index)
    const int j0 = p * TILE;          // j-tile (larger index)
    const bool diag = (p == q);

    __shared__ float2 s_pack[TILE];        // compacted (t_i, r_i) of event-i's
    __shared__ int    s_idx[TILE];         // compacted tid of event-i's (diag check)
    __shared__ unsigned int s_cnt[4];      // per-wave event counts
    __shared__ unsigned int s_part[4][3];

    const int tid  = threadIdx.x;
    const int wid  = tid >> 6;
    const int lane = tid & 63;

    // ---- Stage: compact event-i's into a dense LDS array ----
    {
        int i = i0 + tid;
        bool inb = (i < n);
        float tv = inb ? tim[i]  : 0.0f;
        float rv = inb ? risk[i] : 0.0f;
        bool ev = inb && (evt[i] == 1);
        unsigned long long m = __ballot(ev);
        if (lane == 0) s_cnt[wid] = (unsigned int)__popcll(m);
        __syncthreads();
        int base = 0;
        #pragma unroll
        for (int w = 0; w < 4; ++w) base += (w < wid) ? (int)s_cnt[w] : 0;
        int pos = base + (int)__popcll(m & ((1ull << lane) - 1ull));
        if (ev) { s_pack[pos] = make_float2(tv, rv); s_idx[pos] = tid; }
    }
    __syncthreads();

    int cnt = (int)(s_cnt[0] + s_cnt[1] + s_cnt[2] + s_cnt[3]);
    cnt = __builtin_amdgcn_readfirstlane(cnt);   // scalar loop bound

    // ---- Per-lane j data, register-resident ----
    const int j  = j0 + tid;
    const bool jv = (j < n);
    const float tj = jv ? tim[j]  : 0.0f;
    const float rj = jv ? risk[j] : 0.0f;
    const int  ejv = jv ? evt[j]  : -1;
    const bool ej1 = (ejv == 1);
    const bool ej0 = (ejv == 0);

    unsigned int nComp = 0, nConc = 0, nTie = 0;

    if (!diag) {
        // Off-diagonal: every staged i < every j (j0 >= i0+TILE).
        #pragma unroll 4
        for (int k = 0; k < cnt; ++k) {
            float2 tr = s_pack[k];          // broadcast ds_read_b64
            float ti = tr.x, ri = tr.y;
            bool lt  = ti < tj;
            bool gt  = ti > tj;
            bool rgt = ri > rj;
            bool rlt = ri < rj;
            bool req = ri == rj;
            bool comp = ej1 | (ej0 & lt);
            bool conc = (ej1 & ((lt & rgt) | (gt & rlt))) | (ej0 & lt & rgt);
            nComp += (unsigned int)comp;
            nConc += (unsigned int)conc;
            nTie  += (unsigned int)(comp & req);
        }
    } else {
        // Diagonal tile: j0 == i0, enforce j > i  <=>  tid > staged tid.
        #pragma unroll 4
        for (int k = 0; k < cnt; ++k) {
            float2 tr = s_pack[k];
            int   ii  = s_idx[k];
            float ti = tr.x, ri = tr.y;
            bool ok  = tid > ii;
            bool lt  = ti < tj;
            bool gt  = ti > tj;
            bool rgt = ri > rj;
            bool rlt = ri < rj;
            bool req = ri == rj;
            bool comp = (ej1 | (ej0 & lt)) & ok;
            bool conc = ((ej1 & ((lt & rgt) | (gt & rlt))) | (ej0 & lt & rgt)) & ok;
            nComp += (unsigned int)comp;
            nConc += (unsigned int)conc;
            nTie  += (unsigned int)(comp & req);
        }
    }

    // ---- Wave-level shuffle reduction (64 lanes) ----
    for (int off = 32; off > 0; off >>= 1) {
        nComp += __shfl_down(nComp, off, 64);
        nConc += __shfl_down(nConc, off, 64);
        nTie  += __shfl_down(nTie,  off, 64);
    }
    if (lane == 0) {
        s_part[wid][0] = nConc;
        s_part[wid][1] = nTie;
        s_part[wid][2] = nComp;
    }
    __syncthreads();
    if (tid == 0) {
        unsigned int c0 = 0, c1 = 0, c2 = 0;
        #pragma unroll
        for (int w = 0; w < 4; ++w) {
            c0 += s_part[w][0];
            c1 += s_part[w][1];
            c2 += s_part[w][2];
        }
        part[t] = c0;                // conc
        part[nblk + t] = c1;         // tie
        part[2 * nblk + t] = c2;     // comp
        // Release: partial stores become agent-visible before the flag.
        __hip_atomic_store(&flags[t], MAGIC ^ (unsigned int)t,
                           __ATOMIC_RELEASE, __HIP_MEMORY_SCOPE_AGENT);
    }

    // ---- Block 0 finalizes once all flags are posted ----
    // Safe vs poison (0xAAAAAAAA never equals MAGIC^i) and vs stale flags from
    // a previous replay (stale flags point at identical deterministic partials).
    // 528 blocks all fit co-resident (proven by R5's cooperative launch), so
    // spinning cannot deadlock.
    if (t == 0) {
        for (int i = tid; i < nblk; i += 256) {
            while (__hip_atomic_load(&flags[i], __ATOMIC_ACQUIRE,
                                     __HIP_MEMORY_SCOPE_AGENT)
                   != (MAGIC ^ (unsigned int)i)) {
                __builtin_amdgcn_s_sleep(1);
            }
        }
        __syncthreads();

        unsigned int c0 = 0, c1 = 0, c2 = 0;
        for (int i = tid; i < nblk; i += 256) {
            c0 += __hip_atomic_load(&part[i],            __ATOMIC_RELAXED, __HIP_MEMORY_SCOPE_AGENT);
            c1 += __hip_atomic_load(&part[nblk + i],     __ATOMIC_RELAXED, __HIP_MEMORY_SCOPE_AGENT);
            c2 += __hip_atomic_load(&part[2 * nblk + i], __ATOMIC_RELAXED, __HIP_MEMORY_SCOPE_AGENT);
        }
        for (int off = 32; off > 0; off >>= 1) {
            c0 += __shfl_down(c0, off, 64);
            c1 += __shfl_down(c1, off, 64);
            c2 += __shfl_down(c2, off, 64);
        }
        __syncthreads();   // s_part reuse: prior phase fully read
        if (lane == 0) {
            s_part[wid][0] = c0;
            s_part[wid][1] = c1;
            s_part[wid][2] = c2;
        }
        __syncthreads();
        if (tid == 0) {
            unsigned int t0 = 0, t1 = 0, t2 = 0;
            #pragma unroll
            for (int w = 0; w < 4; ++w) {
                t0 += s_part[w][0];
                t1 += s_part[w][1];
                t2 += s_part[w][2];
            }
            double conc = (double)t0;
            double tie  = (double)t1;
            double comp = (double)t2;
            float c;
            if (comp > 0.0) {
                c = (float)((conc + 0.5 * tie) / comp);
            } else {
                c = 0.5f;
            }
            out[0] = 1.0f - c;
        }
    }
}

extern "C" void kernel_launch(void* const* d_in, const int* in_sizes, int n_in,
                              void* d_out, int out_size, void* d_ws, size_t ws_size,
                              hipStream_t stream)
{
    const float* risk = (const float*)d_in[0];   // (B,1) f32, flat B
    const float* tim  = (const float*)d_in[1];   // (B,)  f32
    const int*   evt  = (const int*)d_in[2];     // (B,)  i32
    float* out = (float*)d_out;
    unsigned int* part  = (unsigned int*)d_ws;

    const int n = in_sizes[1];
    const int nt = (n + TILE - 1) / TILE;        // tile rows (32 for n=8192)
    const int nblk = nt * (nt + 1) / 2;          // triangular tile count (528)
    unsigned int* flags = part + 3 * nblk;

    cindex_onepass_kernel<<<dim3(nblk), 256, 0, stream>>>(
        risk, tim, evt, part, flags, out, n, nblk);
}

// Round 8
// 21.361 us; speedup vs baseline: 1.0821x; 1.0821x over previous
//
#include <hip/hip_runtime.h>

#define TILE 256   // square tile side; block = 256 threads

__global__ __launch_bounds__(256) void cindex_pairs_kernel(
    const float* __restrict__ risk,
    const float* __restrict__ tim,
    const int*   __restrict__ evt,
    unsigned int* __restrict__ part,   // SoA: [0,nblk)=conc, [nblk,2n)=tie, [2n,3n)=comp
    int n, int nblk)
{
    const int t = blockIdx.x;
    // Decode lower-triangle pair (p >= q): p*(p+1)/2 <= t < (p+1)*(p+2)/2
    int p = (int)((sqrtf(8.0f * (float)t + 1.0f) - 1.0f) * 0.5f);
    while ((p + 1) * (p + 2) / 2 <= t) ++p;
    while (p * (p + 1) / 2 > t) --p;
    const int q = t - p * (p + 1) / 2;

    const int i0 = q * TILE;          // i-tile (smaller index)
    const int j0 = p * TILE;          // j-tile (larger index)
    const bool diag = (p == q);

    __shared__ float2 s_ipack[TILE];       // compacted (t,r) of event-i's
    __shared__ int    s_iidx[TILE];        // their original tid (diag check)
    __shared__ float2 s_jpack[TILE];       // j's compacted by type: [cens|event|NaN-pad]
    __shared__ int    s_jorig[TILE];       // their original tid (diag check)
    __shared__ unsigned int s_icnt[4], s_ecnt[4], s_ccnt[4];
    __shared__ unsigned int s_part[4][3];

    const int tid  = threadIdx.x;
    const int wid  = tid >> 6;
    const int lane = tid & 63;

    // ---- Stage: compact event-i's; compact j's by event type ----
    {
        int i = i0 + tid;
        bool ivalid = (i < n);
        float tv = ivalid ? tim[i]  : 0.0f;
        float rv = ivalid ? risk[i] : 0.0f;
        bool iev = ivalid && (evt[i] == 1);

        int j = j0 + tid;
        bool jvalid = (j < n);
        float tjv = jvalid ? tim[j]  : 0.0f;
        float rjv = jvalid ? risk[j] : 0.0f;
        int  e    = jvalid ? evt[j]  : -1;
        bool jev = (e == 1);
        bool jce = (e == 0);

        unsigned long long mi = __ballot(iev);
        unsigned long long me = __ballot(jev);
        unsigned long long mc = __ballot(jce);
        if (lane == 0) {
            s_icnt[wid] = (unsigned int)__popcll(mi);
            s_ecnt[wid] = (unsigned int)__popcll(me);
            s_ccnt[wid] = (unsigned int)__popcll(mc);
        }
        __syncthreads();

        int ib = 0, eb = 0, cb = 0, ncT = 0, neT = 0;
        #pragma unroll
        for (int w = 0; w < 4; ++w) {
            if (w < wid) { ib += (int)s_icnt[w]; eb += (int)s_ecnt[w]; cb += (int)s_ccnt[w]; }
            ncT += (int)s_ccnt[w];
            neT += (int)s_ecnt[w];
        }
        unsigned long long below = (1ull << lane) - 1ull;
        if (iev) {
            int pos = ib + (int)__popcll(mi & below);
            s_ipack[pos] = make_float2(tv, rv);
            s_iidx[pos]  = tid;
        }
        if (jev) {
            int pos = ncT + eb + (int)__popcll(me & below);
            s_jpack[pos] = make_float2(tjv, rjv);
            s_jorig[pos] = tid;
        }
        if (jce) {
            int pos = cb + (int)__popcll(mc & below);
            s_jpack[pos] = make_float2(tjv, rjv);
            s_jorig[pos] = tid;
        }
        // NaN-pad dead slots: all ordered compares -> false -> contributes 0.
        if (tid >= ncT + neT) {
            float nanf_ = __uint_as_float(0x7fc00000u);
            s_jpack[tid] = make_float2(nanf_, nanf_);
            s_jorig[tid] = -1;
        }
        __syncthreads();
    }

    int cnt = (int)(s_icnt[0] + s_icnt[1] + s_icnt[2] + s_icnt[3]);
    cnt = __builtin_amdgcn_readfirstlane(cnt);
    int nc  = (int)(s_ccnt[0] + s_ccnt[1] + s_ccnt[2] + s_ccnt[3]);
    nc  = __builtin_amdgcn_readfirstlane(nc);
    int ne  = (int)(s_ecnt[0] + s_ecnt[1] + s_ecnt[2] + s_ecnt[3]);
    ne  = __builtin_amdgcn_readfirstlane(ne);

    // ---- Per-lane j data (compacted slot = tid), register-resident ----
    float2 jp = s_jpack[tid];
    const float tj = jp.x;
    const float rj = jp.y;
    const int jorig = s_jorig[tid];
    const bool laneEv = (tid >= nc) && (tid < nc + ne);

    unsigned int nComp = 0, nConc = 0, nTie = 0;

    if (!diag) {
        if (laneEv) {
            // event-j: every (event-i, event-j) pair comparable -> hoist nComp.
            nComp = (unsigned int)cnt;
            #pragma unroll 4
            for (int k = 0; k < cnt; ++k) {
                float2 tr = s_ipack[k];          // broadcast ds_read_b64
                float ti = tr.x, ri = tr.y;
                bool lt  = ti < tj;
                bool gt  = ti > tj;
                bool rgt = ri > rj;
                bool rlt = ri < rj;
                bool req = ri == rj;
                bool conc = (lt & rgt) | (gt & rlt);
                nConc += (unsigned int)conc;
                nTie  += (unsigned int)req;
            }
        } else {
            // censored-j (or NaN pad): comparable iff ti < tj.
            #pragma unroll 4
            for (int k = 0; k < cnt; ++k) {
                float2 tr = s_ipack[k];
                float ti = tr.x, ri = tr.y;
                bool lt  = ti < tj;
                bool rgt = ri > rj;
                bool req = ri == rj;
                nComp += (unsigned int)lt;
                nConc += (unsigned int)(lt & rgt);
                nTie  += (unsigned int)(lt & req);
            }
        }
    } else {
        // Diagonal tile: mask every pair with ok = (jorig > iidx).
        if (laneEv) {
            #pragma unroll 4
            for (int k = 0; k < cnt; ++k) {
                float2 tr = s_ipack[k];
                int   ii  = s_iidx[k];
                float ti = tr.x, ri = tr.y;
                bool ok  = jorig > ii;
                bool lt  = ti < tj;
                bool gt  = ti > tj;
                bool rgt = ri > rj;
                bool rlt = ri < rj;
                bool req = ri == rj;
                bool conc = (lt & rgt) | (gt & rlt);
                nComp += (unsigned int)ok;
                nConc += (unsigned int)(ok & conc);
                nTie  += (unsigned int)(ok & req);
            }
        } else {
            #pragma unroll 4
            for (int k = 0; k < cnt; ++k) {
                float2 tr = s_ipack[k];
                int   ii  = s_iidx[k];
                float ti = tr.x, ri = tr.y;
                bool ok  = jorig > ii;
                bool lt  = ti < tj;
                bool rgt = ri > rj;
                bool req = ri == rj;
                bool c   = ok & lt;
                nComp += (unsigned int)c;
                nConc += (unsigned int)(c & rgt);
                nTie  += (unsigned int)(c & req);
            }
        }
    }

    // ---- Wave-level shuffle reduction (64 lanes) ----
    for (int off = 32; off > 0; off >>= 1) {
        nComp += __shfl_down(nComp, off, 64);
        nConc += __shfl_down(nConc, off, 64);
        nTie  += __shfl_down(nTie,  off, 64);
    }
    if (lane == 0) {
        s_part[wid][0] = nConc;
        s_part[wid][1] = nTie;
        s_part[wid][2] = nComp;
    }
    __syncthreads();
    if (tid == 0) {
        unsigned int c0 = 0, c1 = 0, c2 = 0;
        #pragma unroll
        for (int w = 0; w < 4; ++w) {
            c0 += s_part[w][0];
            c1 += s_part[w][1];
            c2 += s_part[w][2];
        }
        part[t] = c0;                // conc
        part[nblk + t] = c1;         // tie
        part[2 * nblk + t] = c2;     // comp
    }
}

__global__ __launch_bounds__(256) void cindex_reduce_kernel(
    const unsigned int* __restrict__ part,
    float* __restrict__ out, int nblk)
{
    const int tid = threadIdx.x;
    unsigned int c0 = 0, c1 = 0, c2 = 0;
    for (int i = tid; i < nblk; i += 256) {
        c0 += part[i];
        c1 += part[nblk + i];
        c2 += part[2 * nblk + i];
    }
    for (int off = 32; off > 0; off >>= 1) {
        c0 += __shfl_down(c0, off, 64);
        c1 += __shfl_down(c1, off, 64);
        c2 += __shfl_down(c2, off, 64);
    }
    __shared__ unsigned int s_part[4][3];
    const int wid  = tid >> 6;
    const int lane = tid & 63;
    if (lane == 0) {
        s_part[wid][0] = c0;
        s_part[wid][1] = c1;
        s_part[wid][2] = c2;
    }
    __syncthreads();
    if (tid == 0) {
        unsigned int t0 = 0, t1 = 0, t2 = 0;
        #pragma unroll
        for (int w = 0; w < 4; ++w) {
            t0 += s_part[w][0];
            t1 += s_part[w][1];
            t2 += s_part[w][2];
        }
        double conc = (double)t0;
        double tie  = (double)t1;
        double comp = (double)t2;
        float c;
        if (comp > 0.0) {
            c = (float)((conc + 0.5 * tie) / comp);
        } else {
            c = 0.5f;
        }
        out[0] = 1.0f - c;
    }
}

extern "C" void kernel_launch(void* const* d_in, const int* in_sizes, int n_in,
                              void* d_out, int out_size, void* d_ws, size_t ws_size,
                              hipStream_t stream)
{
    const float* risk = (const float*)d_in[0];   // (B,1) f32, flat B
    const float* tim  = (const float*)d_in[1];   // (B,)  f32
    const int*   evt  = (const int*)d_in[2];     // (B,)  i32
    float* out = (float*)d_out;
    unsigned int* part = (unsigned int*)d_ws;

    const int n = in_sizes[1];
    const int nt = (n + TILE - 1) / TILE;        // tile rows (32 for n=8192)
    const int nblk = nt * (nt + 1) / 2;          // triangular tile count (528)

    cindex_pairs_kernel<<<dim3(nblk), 256, 0, stream>>>(risk, tim, evt, part, n, nblk);
    cindex_reduce_kernel<<<1, 256, 0, stream>>>(part, out, nblk);
}

// Round 9
// 18.891 us; speedup vs baseline: 1.2236x; 1.1307x over previous
//
#include <hip/hip_runtime.h>

#define TILE 128   // square tile side; block = TILE threads, j per-lane
#define NW   (TILE / 64)   // waves per block

__global__ __launch_bounds__(TILE) void cindex_pairs_kernel(
    const float* __restrict__ risk,
    const float* __restrict__ tim,
    const int*   __restrict__ evt,
    unsigned int* __restrict__ part,   // SoA: [0,nblk)=conc, [nblk,2n)=tie, [2n,3n)=comp
    int n, int nblk)
{
    const int t = blockIdx.x;
    // Decode lower-triangle pair (p >= q): p*(p+1)/2 <= t < (p+1)*(p+2)/2
    int p = (int)((sqrtf(8.0f * (float)t + 1.0f) - 1.0f) * 0.5f);
    while ((p + 1) * (p + 2) / 2 <= t) ++p;
    while (p * (p + 1) / 2 > t) --p;
    const int q = t - p * (p + 1) / 2;

    const int i0 = q * TILE;          // i-tile (smaller index)
    const int j0 = p * TILE;          // j-tile (larger index)
    const bool diag = (p == q);

    __shared__ float2 s_pack[TILE];        // compacted (t_i, r_i) of event-i's
    __shared__ int    s_idx[TILE];         // compacted tid of event-i's (diag check)
    __shared__ unsigned int s_cnt[NW];     // per-wave event counts
    __shared__ unsigned int s_part[NW][3];

    const int tid  = threadIdx.x;
    const int wid  = tid >> 6;
    const int lane = tid & 63;

    // ---- Stage: compact event-i's into a dense LDS array ----
    {
        int i = i0 + tid;
        bool inb = (i < n);
        float tv = inb ? tim[i]  : 0.0f;
        float rv = inb ? risk[i] : 0.0f;
        bool ev = inb && (evt[i] == 1);
        unsigned long long m = __ballot(ev);
        if (lane == 0) s_cnt[wid] = (unsigned int)__popcll(m);
        __syncthreads();
        int base = 0;
        #pragma unroll
        for (int w = 0; w < NW; ++w) base += (w < wid) ? (int)s_cnt[w] : 0;
        int pos = base + (int)__popcll(m & ((1ull << lane) - 1ull));
        if (ev) { s_pack[pos] = make_float2(tv, rv); s_idx[pos] = tid; }
    }
    __syncthreads();

    int cnt = 0;
    #pragma unroll
    for (int w = 0; w < NW; ++w) cnt += (int)s_cnt[w];
    cnt = __builtin_amdgcn_readfirstlane(cnt);   // scalar loop bound

    // ---- Per-lane j data, register-resident ----
    const int j  = j0 + tid;
    const bool jv = (j < n);
    const float tj = jv ? tim[j]  : 0.0f;
    const float rj = jv ? risk[j] : 0.0f;
    const int  ejv = jv ? evt[j]  : -1;
    const bool ej1 = (ejv == 1);
    const bool ej0 = (ejv == 0);

    unsigned int nComp = 0, nConc = 0, nTie = 0;

    if (!diag) {
        // Off-diagonal: every staged i < every j (j0 >= i0+TILE).
        #pragma unroll 4
        for (int k = 0; k < cnt; ++k) {
            float2 tr = s_pack[k];          // broadcast ds_read_b64
            float ti = tr.x, ri = tr.y;
            bool lt  = ti < tj;
            bool gt  = ti > tj;
            bool rgt = ri > rj;
            bool rlt = ri < rj;
            bool req = ri == rj;
            bool comp = ej1 | (ej0 & lt);
            bool conc = (ej1 & ((lt & rgt) | (gt & rlt))) | (ej0 & lt & rgt);
            nComp += (unsigned int)comp;
            nConc += (unsigned int)conc;
            nTie  += (unsigned int)(comp & req);
        }
    } else {
        // Diagonal tile: j0 == i0, enforce j > i  <=>  tid > staged tid.
        #pragma unroll 4
        for (int k = 0; k < cnt; ++k) {
            float2 tr = s_pack[k];
            int   ii  = s_idx[k];
            float ti = tr.x, ri = tr.y;
            bool ok  = tid > ii;
            bool lt  = ti < tj;
            bool gt  = ti > tj;
            bool rgt = ri > rj;
            bool rlt = ri < rj;
            bool req = ri == rj;
            bool comp = (ej1 | (ej0 & lt)) & ok;
            bool conc = ((ej1 & ((lt & rgt) | (gt & rlt))) | (ej0 & lt & rgt)) & ok;
            nComp += (unsigned int)comp;
            nConc += (unsigned int)conc;
            nTie  += (unsigned int)(comp & req);
        }
    }

    // ---- Wave-level shuffle reduction (64 lanes) ----
    for (int off = 32; off > 0; off >>= 1) {
        nComp += __shfl_down(nComp, off, 64);
        nConc += __shfl_down(nConc, off, 64);
        nTie  += __shfl_down(nTie,  off, 64);
    }
    if (lane == 0) {
        s_part[wid][0] = nConc;
        s_part[wid][1] = nTie;
        s_part[wid][2] = nComp;
    }
    __syncthreads();
    if (tid == 0) {
        unsigned int c0 = 0, c1 = 0, c2 = 0;
        #pragma unroll
        for (int w = 0; w < NW; ++w) {
            c0 += s_part[w][0];
            c1 += s_part[w][1];
            c2 += s_part[w][2];
        }
        part[t] = c0;                // conc
        part[nblk + t] = c1;         // tie
        part[2 * nblk + t] = c2;     // comp
    }
}

__global__ __launch_bounds__(256) void cindex_reduce_kernel(
    const unsigned int* __restrict__ part,
    float* __restrict__ out, int nblk)
{
    const int tid = threadIdx.x;
    unsigned int c0 = 0, c1 = 0, c2 = 0;
    for (int i = tid; i < nblk; i += 256) {
        c0 += part[i];
        c1 += part[nblk + i];
        c2 += part[2 * nblk + i];
    }
    for (int off = 32; off > 0; off >>= 1) {
        c0 += __shfl_down(c0, off, 64);
        c1 += __shfl_down(c1, off, 64);
        c2 += __shfl_down(c2, off, 64);
    }
    __shared__ unsigned int s_part[4][3];
    const int wid  = tid >> 6;
    const int lane = tid & 63;
    if (lane == 0) {
        s_part[wid][0] = c0;
        s_part[wid][1] = c1;
        s_part[wid][2] = c2;
    }
    __syncthreads();
    if (tid == 0) {
        unsigned int t0 = 0, t1 = 0, t2 = 0;
        #pragma unroll
        for (int w = 0; w < 4; ++w) {
            t0 += s_part[w][0];
            t1 += s_part[w][1];
            t2 += s_part[w][2];
        }
        double conc = (double)t0;
        double tie  = (double)t1;
        double comp = (double)t2;
        float c;
        if (comp > 0.0) {
            c = (float)((conc + 0.5 * tie) / comp);
        } else {
            c = 0.5f;
        }
        out[0] = 1.0f - c;
    }
}

extern "C" void kernel_launch(void* const* d_in, const int* in_sizes, int n_in,
                              void* d_out, int out_size, void* d_ws, size_t ws_size,
                              hipStream_t stream)
{
    const float* risk = (const float*)d_in[0];   // (B,1) f32, flat B
    const float* tim  = (const float*)d_in[1];   // (B,)  f32
    const int*   evt  = (const int*)d_in[2];     // (B,)  i32
    float* out = (float*)d_out;
    unsigned int* part = (unsigned int*)d_ws;

    const int n = in_sizes[1];
    const int nt = (n + TILE - 1) / TILE;        // tile rows (64 for n=8192)
    const int nblk = nt * (nt + 1) / 2;          // triangular tile count (2080)

    cindex_pairs_kernel<<<dim3(nblk), TILE, 0, stream>>>(risk, tim, evt, part, n, nblk);
    cindex_reduce_kernel<<<1, 256, 0, stream>>>(part, out, nblk);
}

// Round 10
// 18.473 us; speedup vs baseline: 1.2512x; 1.0226x over previous
//
#include <hip/hip_runtime.h>

#define TILE 64    // square tile side; block = 64 threads = 1 wave, j per-lane

__global__ __launch_bounds__(64) void cindex_pairs_kernel(
    const float* __restrict__ risk,
    const float* __restrict__ tim,
    const int*   __restrict__ evt,
    unsigned int* __restrict__ part,   // SoA: [0,nblk)=conc, [nblk,2n)=tie, [2n,3n)=comp
    int n, int nblk)
{
    const int t = blockIdx.x;
    // Decode lower-triangle pair (p >= q): p*(p+1)/2 <= t < (p+1)*(p+2)/2
    int p = (int)((sqrtf(8.0f * (float)t + 1.0f) - 1.0f) * 0.5f);
    while ((p + 1) * (p + 2) / 2 <= t) ++p;
    while (p * (p + 1) / 2 > t) --p;
    const int q = t - p * (p + 1) / 2;

    const int i0 = q * TILE;          // i-tile (smaller index)
    const int j0 = p * TILE;          // j-tile (larger index)
    const bool diag = (p == q);

    __shared__ float2 s_pack[TILE];   // compacted (t_i, r_i) of event-i's
    __shared__ int    s_idx[TILE];    // compacted lane of event-i's (diag check)

    const int tid = threadIdx.x;      // == lane (single-wave block)

    // ---- Stage: compact event-i's into dense LDS, fully in-wave ----
    int cnt;
    {
        int i = i0 + tid;
        bool inb = (i < n);
        float tv = inb ? tim[i]  : 0.0f;
        float rv = inb ? risk[i] : 0.0f;
        bool ev = inb && (evt[i] == 1);
        unsigned long long m = __ballot(ev);
        cnt = (int)__popcll(m);                       // wave-uniform
        int pos = (int)__popcll(m & ((1ull << tid) - 1ull));
        if (ev) { s_pack[pos] = make_float2(tv, rv); s_idx[pos] = tid; }
    }
    __syncthreads();   // single-wave: cheap; orders ds_write -> ds_read
    cnt = __builtin_amdgcn_readfirstlane(cnt);

    // ---- Per-lane j data, register-resident ----
    const int j  = j0 + tid;
    const bool jv = (j < n);
    const float tj = jv ? tim[j]  : 0.0f;
    const float rj = jv ? risk[j] : 0.0f;
    const int  ejv = jv ? evt[j]  : -1;
    const bool ej1 = (ejv == 1);
    const bool ej0 = (ejv == 0);

    unsigned int nComp = 0, nConc = 0, nTie = 0;

    if (!diag) {
        // Off-diagonal: every staged i < every j (j0 >= i0+TILE).
        #pragma unroll 4
        for (int k = 0; k < cnt; ++k) {
            float2 tr = s_pack[k];          // broadcast ds_read_b64
            float ti = tr.x, ri = tr.y;
            bool lt  = ti < tj;
            bool gt  = ti > tj;
            bool rgt = ri > rj;
            bool rlt = ri < rj;
            bool req = ri == rj;
            bool comp = ej1 | (ej0 & lt);
            bool conc = (ej1 & ((lt & rgt) | (gt & rlt))) | (ej0 & lt & rgt);
            nComp += (unsigned int)comp;
            nConc += (unsigned int)conc;
            nTie  += (unsigned int)(comp & req);
        }
    } else {
        // Diagonal tile: j0 == i0, enforce j > i  <=>  tid > staged lane.
        #pragma unroll 4
        for (int k = 0; k < cnt; ++k) {
            float2 tr = s_pack[k];
            int   ii  = s_idx[k];
            float ti = tr.x, ri = tr.y;
            bool ok  = tid > ii;
            bool lt  = ti < tj;
            bool gt  = ti > tj;
            bool rgt = ri > rj;
            bool rlt = ri < rj;
            bool req = ri == rj;
            bool comp = (ej1 | (ej0 & lt)) & ok;
            bool conc = ((ej1 & ((lt & rgt) | (gt & rlt))) | (ej0 & lt & rgt)) & ok;
            nComp += (unsigned int)comp;
            nConc += (unsigned int)conc;
            nTie  += (unsigned int)(comp & req);
        }
    }

    // ---- Wave shuffle reduction; lane 0 stores the block partials ----
    for (int off = 32; off > 0; off >>= 1) {
        nComp += __shfl_down(nComp, off, 64);
        nConc += __shfl_down(nConc, off, 64);
        nTie  += __shfl_down(nTie,  off, 64);
    }
    if (tid == 0) {
        part[t] = nConc;
        part[nblk + t] = nTie;
        part[2 * nblk + t] = nComp;
    }
}

__global__ __launch_bounds__(1024) void cindex_reduce_kernel(
    const unsigned int* __restrict__ part,
    float* __restrict__ out, int nblk)
{
    const int tid = threadIdx.x;
    unsigned int c0 = 0, c1 = 0, c2 = 0;
    for (int i = tid; i < nblk; i += 1024) {
        c0 += part[i];
        c1 += part[nblk + i];
        c2 += part[2 * nblk + i];
    }
    for (int off = 32; off > 0; off >>= 1) {
        c0 += __shfl_down(c0, off, 64);
        c1 += __shfl_down(c1, off, 64);
        c2 += __shfl_down(c2, off, 64);
    }
    __shared__ unsigned int s_part[16][3];
    const int wid  = tid >> 6;
    const int lane = tid & 63;
    if (lane == 0) {
        s_part[wid][0] = c0;
        s_part[wid][1] = c1;
        s_part[wid][2] = c2;
    }
    __syncthreads();
    if (tid == 0) {
        unsigned int t0 = 0, t1 = 0, t2 = 0;
        #pragma unroll
        for (int w = 0; w < 16; ++w) {
            t0 += s_part[w][0];
            t1 += s_part[w][1];
            t2 += s_part[w][2];
        }
        double conc = (double)t0;
        double tie  = (double)t1;
        double comp = (double)t2;
        float c;
        if (comp > 0.0) {
            c = (float)((conc + 0.5 * tie) / comp);
        } else {
            c = 0.5f;
        }
        out[0] = 1.0f - c;
    }
}

extern "C" void kernel_launch(void* const* d_in, const int* in_sizes, int n_in,
                              void* d_out, int out_size, void* d_ws, size_t ws_size,
                              hipStream_t stream)
{
    const float* risk = (const float*)d_in[0];   // (B,1) f32, flat B
    const float* tim  = (const float*)d_in[1];   // (B,)  f32
    const int*   evt  = (const int*)d_in[2];     // (B,)  i32
    float* out = (float*)d_out;
    unsigned int* part = (unsigned int*)d_ws;

    const int n = in_sizes[1];
    const int nt = (n + TILE - 1) / TILE;        // tile rows (128 for n=8192)
    const int nblk = nt * (nt + 1) / 2;          // triangular tile count (8256)

    cindex_pairs_kernel<<<dim3(nblk), TILE, 0, stream>>>(risk, tim, evt, part, n, nblk);
    cindex_reduce_kernel<<<1, 1024, 0, stream>>>(part, out, nblk);
}

// Round 11
// 17.659 us; speedup vs baseline: 1.3090x; 1.0461x over previous
//
#include <hip/hip_runtime.h>

#define TILE 64    // tile side handled by ONE wave, j per-lane
#define WPB  4     // waves (= tiles) per 256-thread block

__global__ __launch_bounds__(256) void cindex_pairs_kernel(
    const float* __restrict__ risk,
    const float* __restrict__ tim,
    const int*   __restrict__ evt,
    unsigned int* __restrict__ part,   // SoA: [0,nslot)=conc, [nslot,2n)=tie, [2n,3n)=comp
    int n, int ntile, int nslot)
{
    const int tid  = threadIdx.x;
    const int wid  = tid >> 6;
    const int lane = tid & 63;
    const int t = blockIdx.x * WPB + wid;   // this wave's tile id

    __shared__ float2 s_pack[WPB][TILE];    // per-wave compacted (t_i, r_i)
    __shared__ int    s_idx[WPB][TILE];     // per-wave compacted lane (diag check)
    __shared__ unsigned int s_part[WPB][3];

    unsigned int nComp = 0, nConc = 0, nTie = 0;
    int cnt = 0;
    int i0 = 0, j0 = 0;
    bool diag = false;
    bool active = (t < ntile);

    if (active) {
        // Decode lower-triangle pair (p >= q): p*(p+1)/2 <= t < (p+1)*(p+2)/2
        int p = (int)((sqrtf(8.0f * (float)t + 1.0f) - 1.0f) * 0.5f);
        while ((p + 1) * (p + 2) / 2 <= t) ++p;
        while (p * (p + 1) / 2 > t) --p;
        const int q = t - p * (p + 1) / 2;
        i0 = q * TILE;
        j0 = p * TILE;
        diag = (p == q);

        // ---- Stage: compact this wave's event-i's into its LDS segment ----
        int i = i0 + lane;
        bool inb = (i < n);
        float tv = inb ? tim[i]  : 0.0f;
        float rv = inb ? risk[i] : 0.0f;
        bool ev = inb && (evt[i] == 1);
        unsigned long long m = __ballot(ev);
        cnt = (int)__popcll(m);                        // wave-uniform
        int pos = (int)__popcll(m & ((1ull << lane) - 1ull));
        if (ev) { s_pack[wid][pos] = make_float2(tv, rv); s_idx[wid][pos] = lane; }
    }
    __syncthreads();   // orders staging ds_writes before loop ds_reads
    cnt = __builtin_amdgcn_readfirstlane(cnt);

    if (active) {
        // ---- Per-lane j data, register-resident ----
        const int j  = j0 + lane;
        const bool jv = (j < n);
        const float tj = jv ? tim[j]  : 0.0f;
        const float rj = jv ? risk[j] : 0.0f;
        const int  ejv = jv ? evt[j]  : -1;
        const bool ej1 = (ejv == 1);
        const bool ej0 = (ejv == 0);

        if (!diag) {
            // Off-diagonal: every staged i < every j (j0 >= i0+TILE).
            #pragma unroll 4
            for (int k = 0; k < cnt; ++k) {
                float2 tr = s_pack[wid][k];      // broadcast ds_read_b64
                float ti = tr.x, ri = tr.y;
                bool lt  = ti < tj;
                bool gt  = ti > tj;
                bool rgt = ri > rj;
                bool rlt = ri < rj;
                bool req = ri == rj;
                bool comp = ej1 | (ej0 & lt);
                bool conc = (ej1 & ((lt & rgt) | (gt & rlt))) | (ej0 & lt & rgt);
                nComp += (unsigned int)comp;
                nConc += (unsigned int)conc;
                nTie  += (unsigned int)(comp & req);
            }
        } else {
            // Diagonal tile: j0 == i0, enforce j > i  <=>  lane > staged lane.
            #pragma unroll 4
            for (int k = 0; k < cnt; ++k) {
                float2 tr = s_pack[wid][k];
                int   ii  = s_idx[wid][k];
                float ti = tr.x, ri = tr.y;
                bool ok  = lane > ii;
                bool lt  = ti < tj;
                bool gt  = ti > tj;
                bool rgt = ri > rj;
                bool rlt = ri < rj;
                bool req = ri == rj;
                bool comp = (ej1 | (ej0 & lt)) & ok;
                bool conc = ((ej1 & ((lt & rgt) | (gt & rlt))) | (ej0 & lt & rgt)) & ok;
                nComp += (unsigned int)comp;
                nConc += (unsigned int)conc;
                nTie  += (unsigned int)(comp & req);
            }
        }
    }

    // ---- Wave shuffle reduction -> per-wave LDS partial ----
    for (int off = 32; off > 0; off >>= 1) {
        nComp += __shfl_down(nComp, off, 64);
        nConc += __shfl_down(nConc, off, 64);
        nTie  += __shfl_down(nTie,  off, 64);
    }
    if (lane == 0) {
        s_part[wid][0] = nConc;
        s_part[wid][1] = nTie;
        s_part[wid][2] = nComp;
    }
    __syncthreads();
    if (tid == 0) {
        unsigned int c0 = 0, c1 = 0, c2 = 0;
        #pragma unroll
        for (int w = 0; w < WPB; ++w) {
            c0 += s_part[w][0];
            c1 += s_part[w][1];
            c2 += s_part[w][2];
        }
        const int b = blockIdx.x;
        part[b] = c0;                // conc
        part[nslot + b] = c1;        // tie
        part[2 * nslot + b] = c2;    // comp
    }
}

__global__ __launch_bounds__(1024) void cindex_reduce_kernel(
    const unsigned int* __restrict__ part,
    float* __restrict__ out, int nslot)
{
    const int tid = threadIdx.x;
    unsigned int c0 = 0, c1 = 0, c2 = 0;
    for (int i = tid; i < nslot; i += 1024) {
        c0 += part[i];
        c1 += part[nslot + i];
        c2 += part[2 * nslot + i];
    }
    for (int off = 32; off > 0; off >>= 1) {
        c0 += __shfl_down(c0, off, 64);
        c1 += __shfl_down(c1, off, 64);
        c2 += __shfl_down(c2, off, 64);
    }
    __shared__ unsigned int s_part[16][3];
    const int wid  = tid >> 6;
    const int lane = tid & 63;
    if (lane == 0) {
        s_part[wid][0] = c0;
        s_part[wid][1] = c1;
        s_part[wid][2] = c2;
    }
    __syncthreads();
    if (tid == 0) {
        unsigned int t0 = 0, t1 = 0, t2 = 0;
        #pragma unroll
        for (int w = 0; w < 16; ++w) {
            t0 += s_part[w][0];
            t1 += s_part[w][1];
            t2 += s_part[w][2];
        }
        double conc = (double)t0;
        double tie  = (double)t1;
        double comp = (double)t2;
        float c;
        if (comp > 0.0) {
            c = (float)((conc + 0.5 * tie) / comp);
        } else {
            c = 0.5f;
        }
        out[0] = 1.0f - c;
    }
}

extern "C" void kernel_launch(void* const* d_in, const int* in_sizes, int n_in,
                              void* d_out, int out_size, void* d_ws, size_t ws_size,
                              hipStream_t stream)
{
    const float* risk = (const float*)d_in[0];   // (B,1) f32, flat B
    const float* tim  = (const float*)d_in[1];   // (B,)  f32
    const int*   evt  = (const int*)d_in[2];     // (B,)  i32
    float* out = (float*)d_out;
    unsigned int* part = (unsigned int*)d_ws;

    const int n = in_sizes[1];
    const int nt = (n + TILE - 1) / TILE;        // tile rows (128 for n=8192)
    const int ntile = nt * (nt + 1) / 2;         // triangular tile count (8256)
    const int nslot = (ntile + WPB - 1) / WPB;   // blocks / partial slots (2064)

    cindex_pairs_kernel<<<dim3(nslot), 256, 0, stream>>>(risk, tim, evt, part,
                                                         n, ntile, nslot);
    cindex_reduce_kernel<<<1, 1024, 0, stream>>>(part, out, nslot);
}